// Round 1
// baseline (2651.724 us; speedup 1.0000x reference)
//
#include <hip/hip_runtime.h>
#include <math.h>

#define FIN 256
#define FMID 128
#define FOUT 40

// ---------------- degree / norm ----------------
__global__ __launch_bounds__(256) void k_init_deg(float* deg, int n) {
    int i = blockIdx.x * 256 + threadIdx.x;
    if (i < n) deg[i] = 1.0f;   // self-loop contributes 1
}

__global__ __launch_bounds__(256) void k_count_deg(const int* __restrict__ dst,
                                                   float* __restrict__ deg, int E) {
    int e = blockIdx.x * 256 + threadIdx.x;
    if (e < E) atomicAdd(&deg[dst[e]], 1.0f);
}

__global__ __launch_bounds__(256) void k_rsqrt(float* deg, int n) {
    int i = blockIdx.x * 256 + threadIdx.x;
    if (i < n) { float d = deg[i]; deg[i] = d > 0.f ? rsqrtf(d) : 0.f; }
}

// ---------------- GEMM1: [M,256] x [256,128] -> [M,128] (f32) ----------------
#define BM 64
#define BN 128
#define BK 32
__global__ __launch_bounds__(256) void k_gemm1(const float* __restrict__ A,
                                               const float* __restrict__ B,
                                               float* __restrict__ C, int M) {
    __shared__ float As[BK][BM + 4];   // transposed: As[k][m], pad keeps b128 alignment
    __shared__ float Bs[BK][BN];

    const int block_row = blockIdx.x * BM;
    const int t  = threadIdx.x;
    const int tx = t & 15;     // 16 col groups of 8
    const int ty = t >> 4;     // 16 row groups of 4

    float acc[4][8] = {};

    for (int k0 = 0; k0 < FIN; k0 += BK) {
        // load A tile: 64 rows x 32 k, transposed into LDS
        {
            int ar = t >> 3;          // 0..31
            int ak = (t & 7) * 4;     // 0,4,...,28
            #pragma unroll
            for (int p = 0; p < 2; ++p) {
                int row = block_row + ar + p * 32;
                float4 v = (row < M) ? *(const float4*)(&A[(size_t)row * FIN + k0 + ak])
                                     : make_float4(0.f, 0.f, 0.f, 0.f);
                As[ak + 0][ar + p * 32] = v.x;
                As[ak + 1][ar + p * 32] = v.y;
                As[ak + 2][ar + p * 32] = v.z;
                As[ak + 3][ar + p * 32] = v.w;
            }
            // load B tile: 32 k-rows x 128 cols
            int br = t >> 5;          // 0..7
            int bc = (t & 31) * 4;    // 0..124
            #pragma unroll
            for (int p = 0; p < 4; ++p) {
                int row = k0 + br + p * 8;
                *(float4*)(&Bs[br + p * 8][bc]) = *(const float4*)(&B[(size_t)row * BN + bc]);
            }
        }
        __syncthreads();
        #pragma unroll
        for (int k = 0; k < BK; ++k) {
            float4 a  = *(const float4*)(&As[k][ty * 4]);
            float4 b0 = *(const float4*)(&Bs[k][tx * 8]);
            float4 b1 = *(const float4*)(&Bs[k][tx * 8 + 4]);
            float av[4] = {a.x, a.y, a.z, a.w};
            float bv[8] = {b0.x, b0.y, b0.z, b0.w, b1.x, b1.y, b1.z, b1.w};
            #pragma unroll
            for (int i = 0; i < 4; ++i)
                #pragma unroll
                for (int j = 0; j < 8; ++j)
                    acc[i][j] += av[i] * bv[j];
        }
        __syncthreads();
    }

    #pragma unroll
    for (int i = 0; i < 4; ++i) {
        int row = block_row + ty * 4 + i;
        if (row < M) {
            float4 c0 = make_float4(acc[i][0], acc[i][1], acc[i][2], acc[i][3]);
            float4 c1 = make_float4(acc[i][4], acc[i][5], acc[i][6], acc[i][7]);
            *(float4*)(&C[(size_t)row * BN + tx * 8])     = c0;
            *(float4*)(&C[(size_t)row * BN + tx * 8 + 4]) = c1;
        }
    }
}

// ---------------- edge aggregation F=128: one wave per edge ----------------
__global__ __launch_bounds__(256) void k_agg128(const float* __restrict__ h,
                                                const int* __restrict__ src,
                                                const int* __restrict__ dst,
                                                const float* __restrict__ dinv,
                                                float* __restrict__ out, int E, int Nn) {
    int gtid = blockIdx.x * 256 + threadIdx.x;
    int wid  = gtid >> 6;
    int lane = threadIdx.x & 63;
    if (wid >= E + Nn) return;
    int s, d;
    if (wid < E) { s = src[wid]; d = dst[wid]; }
    else         { s = wid - E;  d = s; }
    float w = dinv[s] * dinv[d];
    float2 v = *(const float2*)(&h[(size_t)s * FMID + lane * 2]);
    atomicAdd(&out[(size_t)d * FMID + lane * 2],     v.x * w);
    atomicAdd(&out[(size_t)d * FMID + lane * 2 + 1], v.y * w);
}

// ---------------- bias + relu, in place, float4 ----------------
__global__ __launch_bounds__(256) void k_bias_relu(float* __restrict__ h,
                                                   const float* __restrict__ b, int total4) {
    int i = blockIdx.x * 256 + threadIdx.x;
    if (i >= total4) return;
    int j = i & 31;                       // 128/4 col groups
    float4 v  = ((float4*)h)[i];
    float4 bv = *(const float4*)(&b[j * 4]);
    v.x = fmaxf(v.x + bv.x, 0.f);
    v.y = fmaxf(v.y + bv.y, 0.f);
    v.z = fmaxf(v.z + bv.z, 0.f);
    v.w = fmaxf(v.w + bv.w, 0.f);
    ((float4*)h)[i] = v;
}

// ---------------- GEMM2: [M,128] x [128,40] -> [M,40] (f32) ----------------
__global__ __launch_bounds__(256) void k_gemm2(const float* __restrict__ A,
                                               const float* __restrict__ W2,
                                               float* __restrict__ C, int M) {
    __shared__ float w2s[FMID * FOUT];    // 20 KB
    for (int idx = threadIdx.x; idx < FMID * FOUT; idx += 256) w2s[idx] = W2[idx];
    __syncthreads();

    int cg   = threadIdx.x & 7;           // 8 groups x 5 cols
    int rg   = threadIdx.x >> 3;          // 0..31, 2 rows each
    int row0 = blockIdx.x * 64 + rg * 2;
    if (row0 >= M) return;
    int cbase = cg * 5;

    float acc[2][5] = {};
    bool has2 = (row0 + 1 < M);
    for (int k = 0; k < FMID; k += 4) {
        float4 a0 = *(const float4*)(&A[(size_t)row0 * FMID + k]);
        float4 a1 = has2 ? *(const float4*)(&A[(size_t)(row0 + 1) * FMID + k])
                         : make_float4(0.f, 0.f, 0.f, 0.f);
        float a0v[4] = {a0.x, a0.y, a0.z, a0.w};
        float a1v[4] = {a1.x, a1.y, a1.z, a1.w};
        #pragma unroll
        for (int kk = 0; kk < 4; ++kk) {
            #pragma unroll
            for (int j = 0; j < 5; ++j) {
                float w = w2s[(k + kk) * FOUT + cbase + j];
                acc[0][j] += a0v[kk] * w;
                acc[1][j] += a1v[kk] * w;
            }
        }
    }
    #pragma unroll
    for (int r = 0; r < 2; ++r) {
        int row = row0 + r;
        if (row < M)
            for (int j = 0; j < 5; ++j) C[(size_t)row * FOUT + cbase + j] = acc[r][j];
    }
}

// ---------------- edge aggregation F=40 ----------------
__global__ __launch_bounds__(256) void k_agg40(const float* __restrict__ h,
                                               const int* __restrict__ src,
                                               const int* __restrict__ dst,
                                               const float* __restrict__ dinv,
                                               float* __restrict__ out, int E, int Nn) {
    int gtid = blockIdx.x * 256 + threadIdx.x;
    int wid  = gtid >> 6;
    int lane = threadIdx.x & 63;
    if (wid >= E + Nn) return;
    int s, d;
    if (wid < E) { s = src[wid]; d = dst[wid]; }
    else         { s = wid - E;  d = s; }
    if (lane < FOUT) {
        float w = dinv[s] * dinv[d];
        atomicAdd(&out[(size_t)d * FOUT + lane], h[(size_t)s * FOUT + lane] * w);
    }
}

// ---------------- bias + log_softmax, in place on d_out ----------------
__global__ __launch_bounds__(256) void k_logsm(float* __restrict__ out,
                                               const float* __restrict__ b2, int Nn) {
    int gtid = blockIdx.x * 256 + threadIdx.x;
    int wid  = gtid >> 6;
    int lane = threadIdx.x & 63;
    if (wid >= Nn) return;
    float v = (lane < FOUT) ? out[(size_t)wid * FOUT + lane] + b2[lane] : -INFINITY;
    float m = v;
    #pragma unroll
    for (int off = 32; off >= 1; off >>= 1) m = fmaxf(m, __shfl_xor(m, off));
    float e = (lane < FOUT) ? expf(v - m) : 0.f;
    float ssum = e;
    #pragma unroll
    for (int off = 32; off >= 1; off >>= 1) ssum += __shfl_xor(ssum, off);
    if (lane < FOUT) out[(size_t)wid * FOUT + lane] = v - m - logf(ssum);
}

extern "C" void kernel_launch(void* const* d_in, const int* in_sizes, int n_in,
                              void* d_out, int out_size, void* d_ws, size_t ws_size,
                              hipStream_t stream) {
    const float* x  = (const float*)d_in[0];
    const int*   ei = (const int*)d_in[1];
    const float* W1 = (const float*)d_in[2];
    const float* b1 = (const float*)d_in[3];
    const float* W2 = (const float*)d_in[4];
    const float* b2 = (const float*)d_in[5];

    const int N = in_sizes[0] / FIN;     // 100000
    const int E = in_sizes[1] / 2;       // 1600000
    float* out = (float*)d_out;

    float* h1   = (float*)d_ws;                    // N*128
    float* agg1 = h1   + (size_t)N * FMID;         // N*128 (then relu'd in place)
    float* h2   = agg1 + (size_t)N * FMID;         // N*40
    float* dinv = h2   + (size_t)N * FOUT;         // N

    const int* srcp = ei;
    const int* dstp = ei + E;

    hipMemsetAsync(agg1, 0, (size_t)N * FMID * sizeof(float), stream);
    hipMemsetAsync(out,  0, (size_t)N * FOUT * sizeof(float), stream);

    k_init_deg <<<(N + 255) / 256, 256, 0, stream>>>(dinv, N);
    k_count_deg<<<(E + 255) / 256, 256, 0, stream>>>(dstp, dinv, E);
    k_rsqrt    <<<(N + 255) / 256, 256, 0, stream>>>(dinv, N);

    k_gemm1<<<(N + BM - 1) / BM, 256, 0, stream>>>(x, W1, h1, N);

    const int waves = E + N;
    k_agg128<<<(waves + 3) / 4, 256, 0, stream>>>(h1, srcp, dstp, dinv, agg1, E, N);
    k_bias_relu<<<((N * 32) + 255) / 256, 256, 0, stream>>>(agg1, b1, N * 32);

    k_gemm2<<<(N + 63) / 64, 256, 0, stream>>>(agg1, W2, h2, N);
    k_agg40<<<(waves + 3) / 4, 256, 0, stream>>>(h2, srcp, dstp, dinv, out, E, N);

    k_logsm<<<(N + 3) / 4, 256, 0, stream>>>(out, b2, N);
}

// Round 4
// 1253.418 us; speedup vs baseline: 2.1156x; 2.1156x over previous
//
#include <hip/hip_runtime.h>
#include <math.h>

#define FIN 256
#define FMID 128
#define FOUT 40

// ================= CSR build =================
__global__ __launch_bounds__(256) void k_initcounts(int* counts, int n) {
    int i = blockIdx.x * 256 + threadIdx.x;
    if (i < n) counts[i] = 1;              // self-loop
}

__global__ __launch_bounds__(256) void k_count(const int* __restrict__ dst,
                                               int* __restrict__ counts, int E) {
    int e = blockIdx.x * 256 + threadIdx.x;
    if (e < E) atomicAdd(&counts[dst[e]], 1);
}

// block-level inclusive scan + atomic block base -> start[i]; also dinv = rsqrt(count)
__global__ __launch_bounds__(256) void k_alloc(const int* __restrict__ counts,
                                               int* __restrict__ start,
                                               float* __restrict__ dinv,
                                               int* __restrict__ gcnt, int n) {
    __shared__ int s[256];
    __shared__ int base_s;
    int t = threadIdx.x;
    int i = blockIdx.x * 256 + t;
    int c = (i < n) ? counts[i] : 0;
    s[t] = c;
    __syncthreads();
    #pragma unroll
    for (int off = 1; off < 256; off <<= 1) {
        int v = (t >= off) ? s[t - off] : 0;
        __syncthreads();
        s[t] += v;
        __syncthreads();
    }
    if (t == 255) base_s = atomicAdd(gcnt, s[255]);
    __syncthreads();
    if (i < n) {
        start[i] = base_s + s[t] - c;      // exclusive within block + block base
        dinv[i]  = rsqrtf((float)c);       // c >= 1 always
    }
}

__global__ __launch_bounds__(256) void k_fill(const int* __restrict__ src,
                                              const int* __restrict__ dst,
                                              const int* __restrict__ start,
                                              int* __restrict__ cursor,
                                              int* __restrict__ ebuf, int E, int Nn) {
    int tid = blockIdx.x * 256 + threadIdx.x;
    if (tid >= E + Nn) return;
    int s, d;
    if (tid < E) { s = src[tid]; d = dst[tid]; }
    else         { s = tid - E;  d = s; }
    int pos = atomicAdd(&cursor[d], 1);
    ebuf[start[d] + pos] = s;
}

// ================= GEMM1: [M,256] x [256,128] -> [M,128] (f32) =================
#define BM 64
#define BN 128
#define BK 32
__global__ __launch_bounds__(256) void k_gemm1(const float* __restrict__ A,
                                               const float* __restrict__ B,
                                               float* __restrict__ C, int M) {
    __shared__ float As[BK][BM + 4];
    __shared__ float Bs[BK][BN];

    const int block_row = blockIdx.x * BM;
    const int t  = threadIdx.x;
    const int tx = t & 15;
    const int ty = t >> 4;

    float acc[4][8] = {};

    for (int k0 = 0; k0 < FIN; k0 += BK) {
        {
            int ar = t >> 3;
            int ak = (t & 7) * 4;
            #pragma unroll
            for (int p = 0; p < 2; ++p) {
                int row = block_row + ar + p * 32;
                float4 v = (row < M) ? *(const float4*)(&A[(size_t)row * FIN + k0 + ak])
                                     : make_float4(0.f, 0.f, 0.f, 0.f);
                As[ak + 0][ar + p * 32] = v.x;
                As[ak + 1][ar + p * 32] = v.y;
                As[ak + 2][ar + p * 32] = v.z;
                As[ak + 3][ar + p * 32] = v.w;
            }
            int br = t >> 5;
            int bc = (t & 31) * 4;
            #pragma unroll
            for (int p = 0; p < 4; ++p) {
                int row = k0 + br + p * 8;
                *(float4*)(&Bs[br + p * 8][bc]) = *(const float4*)(&B[(size_t)row * BN + bc]);
            }
        }
        __syncthreads();
        #pragma unroll
        for (int k = 0; k < BK; ++k) {
            float4 a  = *(const float4*)(&As[k][ty * 4]);
            float4 b0 = *(const float4*)(&Bs[k][tx * 8]);
            float4 b1 = *(const float4*)(&Bs[k][tx * 8 + 4]);
            float av[4] = {a.x, a.y, a.z, a.w};
            float bv[8] = {b0.x, b0.y, b0.z, b0.w, b1.x, b1.y, b1.z, b1.w};
            #pragma unroll
            for (int i = 0; i < 4; ++i)
                #pragma unroll
                for (int j = 0; j < 8; ++j)
                    acc[i][j] += av[i] * bv[j];
        }
        __syncthreads();
    }

    #pragma unroll
    for (int i = 0; i < 4; ++i) {
        int row = block_row + ty * 4 + i;
        if (row < M) {
            float4 c0 = make_float4(acc[i][0], acc[i][1], acc[i][2], acc[i][3]);
            float4 c1 = make_float4(acc[i][4], acc[i][5], acc[i][6], acc[i][7]);
            *(float4*)(&C[(size_t)row * BN + tx * 8])     = c0;
            *(float4*)(&C[(size_t)row * BN + tx * 8 + 4]) = c1;
        }
    }
}

// ============ agg1 (CSR gather, F=128) + bias + relu, one wave per node ============
__global__ __launch_bounds__(256) void k_agg1(const float* __restrict__ h,
                                              const int* __restrict__ ebuf,
                                              const int* __restrict__ start,
                                              const int* __restrict__ cnt,
                                              const float* __restrict__ dinv,
                                              const float* __restrict__ b1,
                                              float* __restrict__ out, int Nn) {
    int node = __builtin_amdgcn_readfirstlane(blockIdx.x * 4 + (threadIdx.x >> 6));
    int lane = threadIdx.x & 63;
    if (node >= Nn) return;
    int rs = start[node];
    int n  = cnt[node];
    float di = dinv[node];
    float2 acc = make_float2(0.f, 0.f);
    for (int k = 0; k < n; ++k) {
        int s   = ebuf[rs + k];
        float w = di * dinv[s];
        float2 v = *(const float2*)(&h[(size_t)s * FMID + lane * 2]);
        acc.x += w * v.x;
        acc.y += w * v.y;
    }
    float2 bv = *(const float2*)(&b1[lane * 2]);
    acc.x = fmaxf(acc.x + bv.x, 0.f);
    acc.y = fmaxf(acc.y + bv.y, 0.f);
    *(float2*)(&out[(size_t)node * FMID + lane * 2]) = acc;
}

// ================= GEMM2: [M,128] x [128,40] -> [M,40] (f32) =================
__global__ __launch_bounds__(256) void k_gemm2(const float* __restrict__ A,
                                               const float* __restrict__ W2,
                                               float* __restrict__ C, int M) {
    __shared__ float w2s[FMID * FOUT];
    for (int idx = threadIdx.x; idx < FMID * FOUT; idx += 256) w2s[idx] = W2[idx];
    __syncthreads();

    int cg   = threadIdx.x & 7;
    int rg   = threadIdx.x >> 3;
    int row0 = blockIdx.x * 64 + rg * 2;
    if (row0 >= M) return;
    int cbase = cg * 5;

    float acc[2][5] = {};
    bool has2 = (row0 + 1 < M);
    for (int k = 0; k < FMID; k += 4) {
        float4 a0 = *(const float4*)(&A[(size_t)row0 * FMID + k]);
        float4 a1 = has2 ? *(const float4*)(&A[(size_t)(row0 + 1) * FMID + k])
                         : make_float4(0.f, 0.f, 0.f, 0.f);
        float a0v[4] = {a0.x, a0.y, a0.z, a0.w};
        float a1v[4] = {a1.x, a1.y, a1.z, a1.w};
        #pragma unroll
        for (int kk = 0; kk < 4; ++kk) {
            #pragma unroll
            for (int j = 0; j < 5; ++j) {
                float w = w2s[(k + kk) * FOUT + cbase + j];
                acc[0][j] += a0v[kk] * w;
                acc[1][j] += a1v[kk] * w;
            }
        }
    }
    #pragma unroll
    for (int r = 0; r < 2; ++r) {
        int row = row0 + r;
        if (row < M)
            for (int j = 0; j < 5; ++j) C[(size_t)row * FOUT + cbase + j] = acc[r][j];
    }
}

// ====== agg2 (CSR gather, F=40) + bias + log_softmax -> d_out, one wave per node ======
__global__ __launch_bounds__(256) void k_agg2(const float* __restrict__ h,
                                              const int* __restrict__ ebuf,
                                              const int* __restrict__ start,
                                              const int* __restrict__ cnt,
                                              const float* __restrict__ dinv,
                                              const float* __restrict__ b2,
                                              float* __restrict__ out, int Nn) {
    int node = __builtin_amdgcn_readfirstlane(blockIdx.x * 4 + (threadIdx.x >> 6));
    int lane = threadIdx.x & 63;
    if (node >= Nn) return;
    int rs = start[node];
    int n  = cnt[node];
    float di = dinv[node];
    float acc = 0.f;
    bool active = (lane < FOUT);
    for (int k = 0; k < n; ++k) {
        int s   = ebuf[rs + k];
        float w = di * dinv[s];
        if (active) acc += w * h[(size_t)s * FOUT + lane];
    }
    float v = active ? acc + b2[lane] : -INFINITY;
    float m = v;
    #pragma unroll
    for (int off = 32; off >= 1; off >>= 1) m = fmaxf(m, __shfl_xor(m, off));
    float e = active ? expf(v - m) : 0.f;
    float ssum = e;
    #pragma unroll
    for (int off = 32; off >= 1; off >>= 1) ssum += __shfl_xor(ssum, off);
    if (active) out[(size_t)node * FOUT + lane] = v - m - logf(ssum);
}

extern "C" void kernel_launch(void* const* d_in, const int* in_sizes, int n_in,
                              void* d_out, int out_size, void* d_ws, size_t ws_size,
                              hipStream_t stream) {
    const float* x  = (const float*)d_in[0];
    const int*   ei = (const int*)d_in[1];
    const float* W1 = (const float*)d_in[2];
    const float* b1 = (const float*)d_in[3];
    const float* W2 = (const float*)d_in[4];
    const float* b2 = (const float*)d_in[5];

    const int N = in_sizes[0] / FIN;     // 100000
    const int E = in_sizes[1] / 2;       // 1600000
    float* out = (float*)d_out;

    // workspace layout
    float* h1     = (float*)d_ws;                      // N*128 f32 (h2 aliases this later)
    float* agg1   = h1 + (size_t)N * FMID;             // N*128 f32
    float* dinv   = agg1 + (size_t)N * FMID;           // N f32
    int*   counts = (int*)(dinv + N);                  // N int (count, then cursor)
    int*   start  = counts + N;                        // N int
    int*   gcnt   = start + N;                         // 1 int (+ pad)
    int*   ebuf   = gcnt + 64;                         // E+N int
    float* h2     = h1;                                // alias: h1 dead after k_agg1

    const int* srcp = ei;
    const int* dstp = ei + E;
    const int  EN   = E + N;

    // ---- CSR build ----
    hipMemsetAsync(gcnt, 0, sizeof(int), stream);
    k_initcounts<<<(N + 255) / 256, 256, 0, stream>>>(counts, N);
    k_count     <<<(E + 255) / 256, 256, 0, stream>>>(dstp, counts, E);
    k_alloc     <<<(N + 255) / 256, 256, 0, stream>>>(counts, start, dinv, gcnt, N);
    hipMemsetAsync(counts, 0, (size_t)N * sizeof(int), stream);   // reuse as cursor
    k_fill      <<<(EN + 255) / 256, 256, 0, stream>>>(srcp, dstp, start, counts, ebuf, E, N);

    // ---- layer 1 ----
    k_gemm1<<<(N + BM - 1) / BM, 256, 0, stream>>>(x, W1, h1, N);
    k_agg1 <<<(N + 3) / 4, 256, 0, stream>>>(h1, ebuf, start, counts, dinv, b1, agg1, N);

    // ---- layer 2 ----
    k_gemm2<<<(N + 63) / 64, 256, 0, stream>>>(agg1, W2, h2, N);
    k_agg2 <<<(N + 3) / 4, 256, 0, stream>>>(h2, ebuf, start, counts, dinv, b2, out, N);
}

// Round 6
// 677.021 us; speedup vs baseline: 3.9168x; 1.8514x over previous
//
#include <hip/hip_runtime.h>
#include <math.h>

#define FIN 256
#define FMID 128
#define FOUT 40

// ================= CSR build =================
__global__ __launch_bounds__(256) void k_initcounts(int* counts, int n) {
    int i = blockIdx.x * 256 + threadIdx.x;
    if (i < n) counts[i] = 1;              // self-loop
}

__global__ __launch_bounds__(256) void k_count(const int* __restrict__ dst,
                                               int* __restrict__ counts, int E) {
    int e = blockIdx.x * 256 + threadIdx.x;
    if (e < E) atomicAdd(&counts[dst[e]], 1);
}

// block-level inclusive scan + atomic block base -> start[i]; also dinv = rsqrt(count)
__global__ __launch_bounds__(256) void k_alloc(const int* __restrict__ counts,
                                               int* __restrict__ start,
                                               float* __restrict__ dinv,
                                               int* __restrict__ gcnt, int n) {
    __shared__ int s[256];
    __shared__ int base_s;
    int t = threadIdx.x;
    int i = blockIdx.x * 256 + t;
    int c = (i < n) ? counts[i] : 0;
    s[t] = c;
    __syncthreads();
    #pragma unroll
    for (int off = 1; off < 256; off <<= 1) {
        int v = (t >= off) ? s[t - off] : 0;
        __syncthreads();
        s[t] += v;
        __syncthreads();
    }
    if (t == 255) base_s = atomicAdd(gcnt, s[255]);
    __syncthreads();
    if (i < n) {
        start[i] = base_s + s[t] - c;      // exclusive within block + block base
        dinv[i]  = rsqrtf((float)c);       // c >= 1 always
    }
}

__global__ __launch_bounds__(256) void k_fill(const int* __restrict__ src,
                                              const int* __restrict__ dst,
                                              const int* __restrict__ start,
                                              int* __restrict__ cursor,
                                              int* __restrict__ ebuf, int E, int Nn) {
    int tid = blockIdx.x * 256 + threadIdx.x;
    if (tid >= E + Nn) return;
    int s, d;
    if (tid < E) { s = src[tid]; d = dst[tid]; }
    else         { s = tid - E;  d = s; }
    int pos = atomicAdd(&cursor[d], 1);
    ebuf[start[d] + pos] = s;
}

// ================= GEMM1: [M,256] x [256,128] -> [M,128] (f32) =================
#define BM 64
#define BN 128
#define BK 32
__global__ __launch_bounds__(256) void k_gemm1(const float* __restrict__ A,
                                               const float* __restrict__ B,
                                               float* __restrict__ C, int M) {
    __shared__ float As[BK][BM + 4];
    __shared__ float Bs[BK][BN];

    const int block_row = blockIdx.x * BM;
    const int t  = threadIdx.x;
    const int tx = t & 15;
    const int ty = t >> 4;

    float acc[4][8] = {};

    for (int k0 = 0; k0 < FIN; k0 += BK) {
        {
            int ar = t >> 3;
            int ak = (t & 7) * 4;
            #pragma unroll
            for (int p = 0; p < 2; ++p) {
                int row = block_row + ar + p * 32;
                float4 v = (row < M) ? *(const float4*)(&A[(size_t)row * FIN + k0 + ak])
                                     : make_float4(0.f, 0.f, 0.f, 0.f);
                As[ak + 0][ar + p * 32] = v.x;
                As[ak + 1][ar + p * 32] = v.y;
                As[ak + 2][ar + p * 32] = v.z;
                As[ak + 3][ar + p * 32] = v.w;
            }
            int br = t >> 5;
            int bc = (t & 31) * 4;
            #pragma unroll
            for (int p = 0; p < 4; ++p) {
                int row = k0 + br + p * 8;
                *(float4*)(&Bs[br + p * 8][bc]) = *(const float4*)(&B[(size_t)row * BN + bc]);
            }
        }
        __syncthreads();
        #pragma unroll
        for (int k = 0; k < BK; ++k) {
            float4 a  = *(const float4*)(&As[k][ty * 4]);
            float4 b0 = *(const float4*)(&Bs[k][tx * 8]);
            float4 b1 = *(const float4*)(&Bs[k][tx * 8 + 4]);
            float av[4] = {a.x, a.y, a.z, a.w};
            float bv[8] = {b0.x, b0.y, b0.z, b0.w, b1.x, b1.y, b1.z, b1.w};
            #pragma unroll
            for (int i = 0; i < 4; ++i)
                #pragma unroll
                for (int j = 0; j < 8; ++j)
                    acc[i][j] += av[i] * bv[j];
        }
        __syncthreads();
    }

    #pragma unroll
    for (int i = 0; i < 4; ++i) {
        int row = block_row + ty * 4 + i;
        if (row < M) {
            float4 c0 = make_float4(acc[i][0], acc[i][1], acc[i][2], acc[i][3]);
            float4 c1 = make_float4(acc[i][4], acc[i][5], acc[i][6], acc[i][7]);
            *(float4*)(&C[(size_t)row * BN + tx * 8])     = c0;
            *(float4*)(&C[(size_t)row * BN + tx * 8 + 4]) = c1;
        }
    }
}

// ============ agg1 (CSR gather, F=128) + bias + relu, one wave per node ============
__global__ __launch_bounds__(256) void k_agg1(const float* __restrict__ h,
                                              const int* __restrict__ ebuf,
                                              const int* __restrict__ start,
                                              const int* __restrict__ cnt,
                                              const float* __restrict__ dinv,
                                              const float* __restrict__ b1,
                                              float* __restrict__ out, int Nn) {
    int node = __builtin_amdgcn_readfirstlane(blockIdx.x * 4 + (threadIdx.x >> 6));
    int lane = threadIdx.x & 63;
    if (node >= Nn) return;
    int rs = start[node];
    int n  = cnt[node];
    float di = dinv[node];
    float2 acc = make_float2(0.f, 0.f);
    for (int k = 0; k < n; ++k) {
        int s   = ebuf[rs + k];
        float w = di * dinv[s];
        float2 v = *(const float2*)(&h[(size_t)s * FMID + lane * 2]);
        acc.x += w * v.x;
        acc.y += w * v.y;
    }
    float2 bv = *(const float2*)(&b1[lane * 2]);
    acc.x = fmaxf(acc.x + bv.x, 0.f);
    acc.y = fmaxf(acc.y + bv.y, 0.f);
    *(float2*)(&out[(size_t)node * FMID + lane * 2]) = acc;
}

// ========== GEMM2: [M,128] x [128,40] -> [M,40] (f32), LDS-staged A ==========
// Old version: 256 VGPR + scratch spills (WRITE 916MB for a 16MB output) and
// 8x fetch amplification (strided per-thread rows). New: coalesced float4
// stage of a 64x128 A-tile into padded LDS; 2 rows x 5 cols per thread.
#define G2_PAD 132            // 128 + 4: keeps float4 LDS stores aligned, breaks bank aliasing
__global__ __launch_bounds__(256) void k_gemm2(const float* __restrict__ A,
                                               const float* __restrict__ W2,
                                               float* __restrict__ C, int M) {
    __shared__ float w2s[FMID * FOUT];        // 20 KB, [k][j]
    __shared__ float As[64 * G2_PAD];         // 33 KB

    const int t = threadIdx.x;
    const int block_row = blockIdx.x * 64;

    for (int idx = t; idx < FMID * FOUT; idx += 256) w2s[idx] = W2[idx];

    // stage A tile: 64 rows x 128 cols, float4-coalesced (32 float4 per row)
    {
        int r  = t >> 5;            // 0..7
        int c4 = (t & 31) * 4;      // 0..124
        #pragma unroll
        for (int p = 0; p < 8; ++p) {
            int row = block_row + r + p * 8;
            float4 v = (row < M) ? *(const float4*)(&A[(size_t)row * FMID + c4])
                                 : make_float4(0.f, 0.f, 0.f, 0.f);
            *(float4*)(&As[(r + p * 8) * G2_PAD + c4]) = v;
        }
    }
    __syncthreads();

    const int cg    = t & 7;        // 8 col groups x 5 cols
    const int rg    = t >> 3;       // 0..31, 2 rows each
    const int cbase = cg * 5;
    const float* a0p = &As[(rg * 2 + 0) * G2_PAD];
    const float* a1p = &As[(rg * 2 + 1) * G2_PAD];

    float acc0[5] = {}, acc1[5] = {};
    #pragma unroll 4
    for (int k = 0; k < FMID; ++k) {
        float a0 = a0p[k];
        float a1 = a1p[k];
        #pragma unroll
        for (int j = 0; j < 5; ++j) {
            float w = w2s[k * FOUT + cbase + j];
            acc0[j] += a0 * w;
            acc1[j] += a1 * w;
        }
    }

    int row0 = block_row + rg * 2;
    if (row0 < M) {
        #pragma unroll
        for (int j = 0; j < 5; ++j) C[(size_t)row0 * FOUT + cbase + j] = acc0[j];
    }
    if (row0 + 1 < M) {
        #pragma unroll
        for (int j = 0; j < 5; ++j) C[(size_t)(row0 + 1) * FOUT + cbase + j] = acc1[j];
    }
}

// ====== agg2 (CSR gather, F=40) + bias + log_softmax -> d_out, one wave per node ======
__global__ __launch_bounds__(256) void k_agg2(const float* __restrict__ h,
                                              const int* __restrict__ ebuf,
                                              const int* __restrict__ start,
                                              const int* __restrict__ cnt,
                                              const float* __restrict__ dinv,
                                              const float* __restrict__ b2,
                                              float* __restrict__ out, int Nn) {
    int node = __builtin_amdgcn_readfirstlane(blockIdx.x * 4 + (threadIdx.x >> 6));
    int lane = threadIdx.x & 63;
    if (node >= Nn) return;
    int rs = start[node];
    int n  = cnt[node];
    float di = dinv[node];
    float acc = 0.f;
    bool active = (lane < FOUT);
    for (int k = 0; k < n; ++k) {
        int s   = ebuf[rs + k];
        float w = di * dinv[s];
        if (active) acc += w * h[(size_t)s * FOUT + lane];
    }
    float v = active ? acc + b2[lane] : -INFINITY;
    float m = v;
    #pragma unroll
    for (int off = 32; off >= 1; off >>= 1) m = fmaxf(m, __shfl_xor(m, off));
    float e = active ? expf(v - m) : 0.f;
    float ssum = e;
    #pragma unroll
    for (int off = 32; off >= 1; off >>= 1) ssum += __shfl_xor(ssum, off);
    if (active) out[(size_t)node * FOUT + lane] = v - m - logf(ssum);
}

extern "C" void kernel_launch(void* const* d_in, const int* in_sizes, int n_in,
                              void* d_out, int out_size, void* d_ws, size_t ws_size,
                              hipStream_t stream) {
    const float* x  = (const float*)d_in[0];
    const int*   ei = (const int*)d_in[1];
    const float* W1 = (const float*)d_in[2];
    const float* b1 = (const float*)d_in[3];
    const float* W2 = (const float*)d_in[4];
    const float* b2 = (const float*)d_in[5];

    const int N = in_sizes[0] / FIN;     // 100000
    const int E = in_sizes[1] / 2;       // 1600000
    float* out = (float*)d_out;

    // workspace layout
    float* h1     = (float*)d_ws;                      // N*128 f32 (h2 aliases this later)
    float* agg1   = h1 + (size_t)N * FMID;             // N*128 f32
    float* dinv   = agg1 + (size_t)N * FMID;           // N f32
    int*   counts = (int*)(dinv + N);                  // N int (count, then cursor)
    int*   start  = counts + N;                        // N int
    int*   gcnt   = start + N;                         // 1 int (+ pad)
    int*   ebuf   = gcnt + 64;                         // E+N int
    float* h2     = h1;                                // alias: h1 dead after k_agg1

    const int* srcp = ei;
    const int* dstp = ei + E;
    const int  EN   = E + N;

    // ---- CSR build ----
    hipMemsetAsync(gcnt, 0, sizeof(int), stream);
    k_initcounts<<<(N + 255) / 256, 256, 0, stream>>>(counts, N);
    k_count     <<<(E + 255) / 256, 256, 0, stream>>>(dstp, counts, E);
    k_alloc     <<<(N + 255) / 256, 256, 0, stream>>>(counts, start, dinv, gcnt, N);
    hipMemsetAsync(counts, 0, (size_t)N * sizeof(int), stream);   // reuse as cursor
    k_fill      <<<(EN + 255) / 256, 256, 0, stream>>>(srcp, dstp, start, counts, ebuf, E, N);

    // ---- layer 1 ----
    k_gemm1<<<(N + BM - 1) / BM, 256, 0, stream>>>(x, W1, h1, N);
    k_agg1 <<<(N + 3) / 4, 256, 0, stream>>>(h1, ebuf, start, counts, dinv, b1, agg1, N);

    // ---- layer 2 ----
    k_gemm2<<<(N + 63) / 64, 256, 0, stream>>>(agg1, W2, h2, N);
    k_agg2 <<<(N + 3) / 4, 256, 0, stream>>>(h2, ebuf, start, counts, dinv, b2, out, N);
}

// Round 8
// 617.919 us; speedup vs baseline: 4.2914x; 1.0956x over previous
//
#include <hip/hip_runtime.h>
#include <hip/hip_bf16.h>
#include <math.h>

#define FIN 256
#define FMID 128
#define FOUT 40

typedef __attribute__((ext_vector_type(8))) short bf16x8;
typedef __attribute__((ext_vector_type(4))) float f32x4;

__device__ __forceinline__ short f2b(float f) {
    __hip_bfloat16 h = __float2bfloat16(f);
    return *reinterpret_cast<short*>(&h);
}

// ================= CSR build =================
__global__ __launch_bounds__(256) void k_initcounts(int* counts, int n) {
    int i = blockIdx.x * 256 + threadIdx.x;
    if (i < n) counts[i] = 1;              // self-loop
}

__global__ __launch_bounds__(256) void k_count(const int* __restrict__ dst,
                                               int* __restrict__ counts, int E) {
    int e = blockIdx.x * 256 + threadIdx.x;
    if (e < E) atomicAdd(&counts[dst[e]], 1);
}

__global__ __launch_bounds__(256) void k_alloc(const int* __restrict__ counts,
                                               int* __restrict__ start,
                                               float* __restrict__ dinv,
                                               int* __restrict__ gcnt, int n) {
    __shared__ int s[256];
    __shared__ int base_s;
    int t = threadIdx.x;
    int i = blockIdx.x * 256 + t;
    int c = (i < n) ? counts[i] : 0;
    s[t] = c;
    __syncthreads();
    #pragma unroll
    for (int off = 1; off < 256; off <<= 1) {
        int v = (t >= off) ? s[t - off] : 0;
        __syncthreads();
        s[t] += v;
        __syncthreads();
    }
    if (t == 255) base_s = atomicAdd(gcnt, s[255]);
    __syncthreads();
    if (i < n) {
        start[i] = base_s + s[t] - c;
        dinv[i]  = rsqrtf((float)c);
    }
}

__global__ __launch_bounds__(256) void k_fill(const int* __restrict__ src,
                                              const int* __restrict__ dst,
                                              const int* __restrict__ start,
                                              int* __restrict__ cursor,
                                              int* __restrict__ ebuf, int E, int Nn) {
    int tid = blockIdx.x * 256 + threadIdx.x;
    if (tid >= E + Nn) return;
    int s, d;
    if (tid < E) { s = src[tid]; d = dst[tid]; }
    else         { s = tid - E;  d = s; }
    int pos = atomicAdd(&cursor[d], 1);
    ebuf[start[d] + pos] = s;
}

// ============ W1 -> bf16, transposed: w1t[n][k], n<128, k<256 ============
__global__ __launch_bounds__(256) void k_prepw1(const float* __restrict__ W1,
                                                short* __restrict__ w1t) {
    int t = blockIdx.x * 256 + threadIdx.x;   // 32768 total
    if (t >= FIN * FMID) return;
    int k = t >> 7;           // 0..255
    int n = t & 127;          // 0..127
    w1t[n * FIN + k] = f2b(W1[t]);
}

// ========== GEMM1 (MFMA bf16): [M,256]f32 x W1 -> [M,128]bf16 ==========
// Block: 256 thr = 4 waves, 128 rows (2 rowtiles of 16 per wave).
// W1^T staged in LDS: 128 rows x 256 bf16 = exactly 64 KB, XOR-swizzled
// (el ^= (n&7)<<3) to break the 512B-pitch bank conflict (T2 recipe).
// K-slot order cancels between A and B frags (same permutation both sides).
__global__ __launch_bounds__(256) void k_gemm1b(const float* __restrict__ A,
                                                const short* __restrict__ w1t,
                                                ushort* __restrict__ Cb, int M) {
    __shared__ short Bs[FMID * FIN];          // 64 KB

    const int t = threadIdx.x;
    // stage w1t -> LDS, 16B chunks, swizzled dst
    {
        int c  = t & 31;        // 32 chunks of 8 bf16 per row
        int r0 = t >> 5;        // 8 rows per pass
        #pragma unroll
        for (int p = 0; p < 16; ++p) {
            int n = r0 + p * 8;
            int dst = n * FIN + ((c * 8) ^ ((n & 7) << 3));
            *(bf16x8*)(&Bs[dst]) = *(const bf16x8*)(&w1t[n * FIN + c * 8]);
        }
    }
    __syncthreads();

    const int wid  = t >> 6;        // 0..3
    const int lane = t & 63;
    const int l15  = lane & 15;
    const int kg   = lane >> 4;     // 0..3
    const int mbase = blockIdx.x * 128 + wid * 32;

    f32x4 acc[2][8] = {};

    for (int ks = 0; ks < 8; ++ks) {
        const int k0 = ks * 32;
        bf16x8 bf[8];
        #pragma unroll
        for (int ct = 0; ct < 8; ++ct) {
            int n = ct * 16 + l15;
            bf[ct] = *(const bf16x8*)(&Bs[n * FIN + ((k0 + kg * 8) ^ ((n & 7) << 3))]);
        }
        #pragma unroll
        for (int rt = 0; rt < 2; ++rt) {
            int row = mbase + rt * 16 + l15;
            bf16x8 af = {0, 0, 0, 0, 0, 0, 0, 0};
            if (row < M) {
                const float* ap = &A[(size_t)row * FIN + k0 + kg * 8];
                float4 a0 = *(const float4*)(ap);
                float4 a1 = *(const float4*)(ap + 4);
                af[0] = f2b(a0.x); af[1] = f2b(a0.y);
                af[2] = f2b(a0.z); af[3] = f2b(a0.w);
                af[4] = f2b(a1.x); af[5] = f2b(a1.y);
                af[6] = f2b(a1.z); af[7] = f2b(a1.w);
            }
            #pragma unroll
            for (int ct = 0; ct < 8; ++ct)
                acc[rt][ct] = __builtin_amdgcn_mfma_f32_16x16x32_bf16(
                    af, bf[ct], acc[rt][ct], 0, 0, 0);
        }
    }

    // D: col = lane&15, row = (lane>>4)*4 + reg   [m89]
    #pragma unroll
    for (int rt = 0; rt < 2; ++rt) {
        #pragma unroll
        for (int r = 0; r < 4; ++r) {
            int row = mbase + rt * 16 + kg * 4 + r;
            if (row < M) {
                #pragma unroll
                for (int ct = 0; ct < 8; ++ct)
                    Cb[(size_t)row * FMID + ct * 16 + l15] =
                        (ushort)f2b(acc[rt][ct][r]);
            }
        }
    }
}

// ====== agg1 (CSR gather, bf16 h, F=128) + bias + relu, one wave per node ======
__global__ __launch_bounds__(256) void k_agg1(const ushort* __restrict__ hb,
                                              const int* __restrict__ ebuf,
                                              const int* __restrict__ start,
                                              const int* __restrict__ cnt,
                                              const float* __restrict__ dinv,
                                              const float* __restrict__ b1,
                                              float* __restrict__ out, int Nn) {
    int node = __builtin_amdgcn_readfirstlane(blockIdx.x * 4 + (threadIdx.x >> 6));
    int lane = threadIdx.x & 63;
    if (node >= Nn) return;
    int rs = start[node];
    int n  = cnt[node];
    float di = dinv[node];
    float2 acc = make_float2(0.f, 0.f);
    for (int k = 0; k < n; ++k) {
        int s   = ebuf[rs + k];
        float w = di * dinv[s];
        uint bits = *(const uint*)(&hb[(size_t)s * FMID + lane * 2]);
        union { uint u; float f; } lo, hi;
        lo.u = bits << 16;            // element 0 (low address)
        hi.u = bits & 0xFFFF0000u;    // element 1
        acc.x += w * lo.f;
        acc.y += w * hi.f;
    }
    float2 bv = *(const float2*)(&b1[lane * 2]);
    acc.x = fmaxf(acc.x + bv.x, 0.f);
    acc.y = fmaxf(acc.y + bv.y, 0.f);
    *(float2*)(&out[(size_t)node * FMID + lane * 2]) = acc;
}

// ========== GEMM2: [M,128] x [128,40] -> [M,40] (f32), LDS-staged A ==========
#define G2_PAD 132
__global__ __launch_bounds__(256) void k_gemm2(const float* __restrict__ A,
                                               const float* __restrict__ W2,
                                               float* __restrict__ C, int M) {
    __shared__ float w2s[FMID * FOUT];        // 20 KB
    __shared__ float As[64 * G2_PAD];         // 33 KB

    const int t = threadIdx.x;
    const int block_row = blockIdx.x * 64;

    for (int idx = t; idx < FMID * FOUT; idx += 256) w2s[idx] = W2[idx];

    {
        int r  = t >> 5;
        int c4 = (t & 31) * 4;
        #pragma unroll
        for (int p = 0; p < 8; ++p) {
            int row = block_row + r + p * 8;
            float4 v = (row < M) ? *(const float4*)(&A[(size_t)row * FMID + c4])
                                 : make_float4(0.f, 0.f, 0.f, 0.f);
            *(float4*)(&As[(r + p * 8) * G2_PAD + c4]) = v;
        }
    }
    __syncthreads();

    const int cg    = t & 7;
    const int rg    = t >> 3;
    const int cbase = cg * 5;
    const float* a0p = &As[(rg * 2 + 0) * G2_PAD];
    const float* a1p = &As[(rg * 2 + 1) * G2_PAD];

    float acc0[5] = {}, acc1[5] = {};
    #pragma unroll 4
    for (int k = 0; k < FMID; ++k) {
        float a0 = a0p[k];
        float a1 = a1p[k];
        #pragma unroll
        for (int j = 0; j < 5; ++j) {
            float w = w2s[k * FOUT + cbase + j];
            acc0[j] += a0 * w;
            acc1[j] += a1 * w;
        }
    }

    int row0 = block_row + rg * 2;
    if (row0 < M) {
        #pragma unroll
        for (int j = 0; j < 5; ++j) C[(size_t)row0 * FOUT + cbase + j] = acc0[j];
    }
    if (row0 + 1 < M) {
        #pragma unroll
        for (int j = 0; j < 5; ++j) C[(size_t)(row0 + 1) * FOUT + cbase + j] = acc1[j];
    }
}

// ====== agg2 (CSR gather, F=40) + bias + log_softmax -> d_out ======
__global__ __launch_bounds__(256) void k_agg2(const float* __restrict__ h,
                                              const int* __restrict__ ebuf,
                                              const int* __restrict__ start,
                                              const int* __restrict__ cnt,
                                              const float* __restrict__ dinv,
                                              const float* __restrict__ b2,
                                              float* __restrict__ out, int Nn) {
    int node = __builtin_amdgcn_readfirstlane(blockIdx.x * 4 + (threadIdx.x >> 6));
    int lane = threadIdx.x & 63;
    if (node >= Nn) return;
    int rs = start[node];
    int n  = cnt[node];
    float di = dinv[node];
    float acc = 0.f;
    bool active = (lane < FOUT);
    for (int k = 0; k < n; ++k) {
        int s   = ebuf[rs + k];
        float w = di * dinv[s];
        if (active) acc += w * h[(size_t)s * FOUT + lane];
    }
    float v = active ? acc + b2[lane] : -INFINITY;
    float m = v;
    #pragma unroll
    for (int off = 32; off >= 1; off >>= 1) m = fmaxf(m, __shfl_xor(m, off));
    float e = active ? expf(v - m) : 0.f;
    float ssum = e;
    #pragma unroll
    for (int off = 32; off >= 1; off >>= 1) ssum += __shfl_xor(ssum, off);
    if (active) out[(size_t)node * FOUT + lane] = v - m - logf(ssum);
}

extern "C" void kernel_launch(void* const* d_in, const int* in_sizes, int n_in,
                              void* d_out, int out_size, void* d_ws, size_t ws_size,
                              hipStream_t stream) {
    const float* x  = (const float*)d_in[0];
    const int*   ei = (const int*)d_in[1];
    const float* W1 = (const float*)d_in[2];
    const float* b1 = (const float*)d_in[3];
    const float* W2 = (const float*)d_in[4];
    const float* b2 = (const float*)d_in[5];

    const int N = in_sizes[0] / FIN;     // 100000
    const int E = in_sizes[1] / 2;       // 1600000
    float* out = (float*)d_out;

    // workspace layout (~85 MB)
    ushort* h1b   = (ushort*)d_ws;                     // N*128 bf16
    float*  agg1  = (float*)(h1b + (size_t)N * FMID);  // N*128 f32
    float*  dinv  = agg1 + (size_t)N * FMID;           // N f32
    int*    counts= (int*)(dinv + N);                  // N int
    int*    start = counts + N;                        // N int
    int*    gcnt  = start + N;                         // 1 int (+pad)
    int*    ebuf  = gcnt + 64;                         // E+N int
    short*  w1t   = (short*)(ebuf + (size_t)(E + N));  // 128*256 bf16
    float*  h2    = (float*)h1b;                       // alias: h1b dead after k_agg1 (N*40 f32 fits)

    const int* srcp = ei;
    const int* dstp = ei + E;
    const int  EN   = E + N;

    // ---- W1 prep (independent) ----
    k_prepw1<<<(FIN * FMID + 255) / 256, 256, 0, stream>>>(W1, w1t);

    // ---- CSR build ----
    hipMemsetAsync(gcnt, 0, sizeof(int), stream);
    k_initcounts<<<(N + 255) / 256, 256, 0, stream>>>(counts, N);
    k_count     <<<(E + 255) / 256, 256, 0, stream>>>(dstp, counts, E);
    k_alloc     <<<(N + 255) / 256, 256, 0, stream>>>(counts, start, dinv, gcnt, N);
    hipMemsetAsync(counts, 0, (size_t)N * sizeof(int), stream);   // reuse as cursor
    k_fill      <<<(EN + 255) / 256, 256, 0, stream>>>(srcp, dstp, start, counts, ebuf, E, N);

    // ---- layer 1 ----
    k_gemm1b<<<(N + 127) / 128, 256, 0, stream>>>(x, w1t, h1b, N);
    k_agg1  <<<(N + 3) / 4, 256, 0, stream>>>(h1b, ebuf, start, counts, dinv, b1, agg1, N);

    // ---- layer 2 ----
    k_gemm2<<<(N + 63) / 64, 256, 0, stream>>>(agg1, W2, h2, N);
    k_agg2 <<<(N + 3) / 4, 256, 0, stream>>>(h2, ebuf, start, counts, dinv, b2, out, N);
}

// Round 9
// 521.927 us; speedup vs baseline: 5.0806x; 1.1839x over previous
//
#include <hip/hip_runtime.h>
#include <hip/hip_bf16.h>
#include <math.h>

#define FIN 256
#define FMID 128
#define FOUT 40

typedef __attribute__((ext_vector_type(8))) short bf16x8;
typedef __attribute__((ext_vector_type(4))) float f32x4;

__device__ __forceinline__ short f2b(float f) {
    __hip_bfloat16 h = __float2bfloat16(f);
    return *reinterpret_cast<short*>(&h);
}

__device__ __forceinline__ float blo(uint b) { union { uint u; float f; } v; v.u = b << 16; return v.f; }
__device__ __forceinline__ float bhi(uint b) { union { uint u; float f; } v; v.u = b & 0xFFFF0000u; return v.f; }

// ================= CSR build =================
__global__ __launch_bounds__(256) void k_initcounts(int* counts, int n) {
    int i = blockIdx.x * 256 + threadIdx.x;
    if (i < n) counts[i] = 1;              // self-loop
}

__global__ __launch_bounds__(256) void k_count(const int* __restrict__ dst,
                                               int* __restrict__ counts, int E) {
    int e = blockIdx.x * 256 + threadIdx.x;
    if (e < E) atomicAdd(&counts[dst[e]], 1);
}

__global__ __launch_bounds__(256) void k_alloc(const int* __restrict__ counts,
                                               int* __restrict__ start,
                                               float* __restrict__ dinv,
                                               int* __restrict__ gcnt, int n) {
    __shared__ int s[256];
    __shared__ int base_s;
    int t = threadIdx.x;
    int i = blockIdx.x * 256 + t;
    int c = (i < n) ? counts[i] : 0;
    s[t] = c;
    __syncthreads();
    #pragma unroll
    for (int off = 1; off < 256; off <<= 1) {
        int v = (t >= off) ? s[t - off] : 0;
        __syncthreads();
        s[t] += v;
        __syncthreads();
    }
    if (t == 255) base_s = atomicAdd(gcnt, s[255]);
    __syncthreads();
    if (i < n) {
        start[i] = base_s + s[t] - c;
        dinv[i]  = rsqrtf((float)c);
    }
}

__global__ __launch_bounds__(256) void k_fill(const int* __restrict__ src,
                                              const int* __restrict__ dst,
                                              const int* __restrict__ start,
                                              int* __restrict__ cursor,
                                              int* __restrict__ ebuf, int E, int Nn) {
    int tid = blockIdx.x * 256 + threadIdx.x;
    if (tid >= E + Nn) return;
    int s, d;
    if (tid < E) { s = src[tid]; d = dst[tid]; }
    else         { s = tid - E;  d = s; }
    int pos = atomicAdd(&cursor[d], 1);
    ebuf[start[d] + pos] = s;
}

// ============ W1 -> bf16, transposed: w1t[n][k], n<128, k<256 ============
__global__ __launch_bounds__(256) void k_prepw1(const float* __restrict__ W1,
                                                short* __restrict__ w1t) {
    int t = blockIdx.x * 256 + threadIdx.x;   // 32768 total
    if (t >= FIN * FMID) return;
    int k = t >> 7;           // 0..255
    int n = t & 127;          // 0..127
    w1t[n * FIN + k] = f2b(W1[t]);
}

// ========== GEMM1 (MFMA bf16): [M,256]f32 x W1 -> [M,128]bf16 ==========
__global__ __launch_bounds__(256) void k_gemm1b(const float* __restrict__ A,
                                                const short* __restrict__ w1t,
                                                ushort* __restrict__ Cb, int M) {
    __shared__ short Bs[FMID * FIN];          // 64 KB

    const int t = threadIdx.x;
    {
        int c  = t & 31;
        int r0 = t >> 5;
        #pragma unroll
        for (int p = 0; p < 16; ++p) {
            int n = r0 + p * 8;
            int dst = n * FIN + ((c * 8) ^ ((n & 7) << 3));
            *(bf16x8*)(&Bs[dst]) = *(const bf16x8*)(&w1t[n * FIN + c * 8]);
        }
    }
    __syncthreads();

    const int wid  = t >> 6;
    const int lane = t & 63;
    const int l15  = lane & 15;
    const int kg   = lane >> 4;
    const int mbase = blockIdx.x * 128 + wid * 32;

    f32x4 acc[2][8] = {};

    for (int ks = 0; ks < 8; ++ks) {
        const int k0 = ks * 32;
        bf16x8 bf[8];
        #pragma unroll
        for (int ct = 0; ct < 8; ++ct) {
            int n = ct * 16 + l15;
            bf[ct] = *(const bf16x8*)(&Bs[n * FIN + ((k0 + kg * 8) ^ ((n & 7) << 3))]);
        }
        #pragma unroll
        for (int rt = 0; rt < 2; ++rt) {
            int row = mbase + rt * 16 + l15;
            bf16x8 af = {0, 0, 0, 0, 0, 0, 0, 0};
            if (row < M) {
                const float* ap = &A[(size_t)row * FIN + k0 + kg * 8];
                float4 a0 = *(const float4*)(ap);
                float4 a1 = *(const float4*)(ap + 4);
                af[0] = f2b(a0.x); af[1] = f2b(a0.y);
                af[2] = f2b(a0.z); af[3] = f2b(a0.w);
                af[4] = f2b(a1.x); af[5] = f2b(a1.y);
                af[6] = f2b(a1.z); af[7] = f2b(a1.w);
            }
            #pragma unroll
            for (int ct = 0; ct < 8; ++ct)
                acc[rt][ct] = __builtin_amdgcn_mfma_f32_16x16x32_bf16(
                    af, bf[ct], acc[rt][ct], 0, 0, 0);
        }
    }

    #pragma unroll
    for (int rt = 0; rt < 2; ++rt) {
        #pragma unroll
        for (int r = 0; r < 4; ++r) {
            int row = mbase + rt * 16 + kg * 4 + r;
            if (row < M) {
                #pragma unroll
                for (int ct = 0; ct < 8; ++ct)
                    Cb[(size_t)row * FMID + ct * 16 + l15] =
                        (ushort)f2b(acc[rt][ct][r]);
            }
        }
    }
}

// ====== agg1 (CSR gather, bf16 h, F=128) + bias + relu, one wave per node ======
// 4x hand-unrolled: batches the edge-index loads, dinv loads, and row gathers
// so 4 independent memory ops are in flight (latency-bound fix, round-8 PMC).
__global__ __launch_bounds__(256) void k_agg1(const ushort* __restrict__ hb,
                                              const int* __restrict__ ebuf,
                                              const int* __restrict__ start,
                                              const int* __restrict__ cnt,
                                              const float* __restrict__ dinv,
                                              const float* __restrict__ b1,
                                              float* __restrict__ out, int Nn) {
    int node = __builtin_amdgcn_readfirstlane(blockIdx.x * 4 + (threadIdx.x >> 6));
    int lane = threadIdx.x & 63;
    if (node >= Nn) return;
    int rs = start[node];
    int n  = cnt[node];
    float di = dinv[node];
    float2 acc = make_float2(0.f, 0.f);
    const int off2 = lane * 2;
    int k = 0;
    for (; k + 4 <= n; k += 4) {
        int s0 = ebuf[rs + k + 0];
        int s1 = ebuf[rs + k + 1];
        int s2 = ebuf[rs + k + 2];
        int s3 = ebuf[rs + k + 3];
        float w0 = dinv[s0], w1 = dinv[s1], w2 = dinv[s2], w3 = dinv[s3];
        uint v0 = *(const uint*)(&hb[(size_t)s0 * FMID + off2]);
        uint v1 = *(const uint*)(&hb[(size_t)s1 * FMID + off2]);
        uint v2 = *(const uint*)(&hb[(size_t)s2 * FMID + off2]);
        uint v3 = *(const uint*)(&hb[(size_t)s3 * FMID + off2]);
        acc.x += w0 * blo(v0) + w1 * blo(v1) + w2 * blo(v2) + w3 * blo(v3);
        acc.y += w0 * bhi(v0) + w1 * bhi(v1) + w2 * bhi(v2) + w3 * bhi(v3);
    }
    for (; k < n; ++k) {
        int s   = ebuf[rs + k];
        float w = dinv[s];
        uint v  = *(const uint*)(&hb[(size_t)s * FMID + off2]);
        acc.x += w * blo(v);
        acc.y += w * bhi(v);
    }
    float2 bv = *(const float2*)(&b1[off2]);
    acc.x = fmaxf(di * acc.x + bv.x, 0.f);
    acc.y = fmaxf(di * acc.y + bv.y, 0.f);
    *(float2*)(&out[(size_t)node * FMID + off2]) = acc;
}

// ========== GEMM2: [M,128] x [128,40] -> [M,40] (f32), LDS-staged A ==========
#define G2_PAD 132
__global__ __launch_bounds__(256) void k_gemm2(const float* __restrict__ A,
                                               const float* __restrict__ W2,
                                               float* __restrict__ C, int M) {
    __shared__ float w2s[FMID * FOUT];        // 20 KB
    __shared__ float As[64 * G2_PAD];         // 33 KB

    const int t = threadIdx.x;
    const int block_row = blockIdx.x * 64;

    for (int idx = t; idx < FMID * FOUT; idx += 256) w2s[idx] = W2[idx];

    {
        int r  = t >> 5;
        int c4 = (t & 31) * 4;
        #pragma unroll
        for (int p = 0; p < 8; ++p) {
            int row = block_row + r + p * 8;
            float4 v = (row < M) ? *(const float4*)(&A[(size_t)row * FMID + c4])
                                 : make_float4(0.f, 0.f, 0.f, 0.f);
            *(float4*)(&As[(r + p * 8) * G2_PAD + c4]) = v;
        }
    }
    __syncthreads();

    const int cg    = t & 7;
    const int rg    = t >> 3;
    const int cbase = cg * 5;
    const float* a0p = &As[(rg * 2 + 0) * G2_PAD];
    const float* a1p = &As[(rg * 2 + 1) * G2_PAD];

    float acc0[5] = {}, acc1[5] = {};
    #pragma unroll 4
    for (int k = 0; k < FMID; ++k) {
        float a0 = a0p[k];
        float a1 = a1p[k];
        #pragma unroll
        for (int j = 0; j < 5; ++j) {
            float w = w2s[k * FOUT + cbase + j];
            acc0[j] += a0 * w;
            acc1[j] += a1 * w;
        }
    }

    int row0 = block_row + rg * 2;
    if (row0 < M) {
        #pragma unroll
        for (int j = 0; j < 5; ++j) C[(size_t)row0 * FOUT + cbase + j] = acc0[j];
    }
    if (row0 + 1 < M) {
        #pragma unroll
        for (int j = 0; j < 5; ++j) C[(size_t)(row0 + 1) * FOUT + cbase + j] = acc1[j];
    }
}

// ====== agg2 (CSR gather, F=40) + bias + log_softmax -> d_out, 4x unrolled ======
__global__ __launch_bounds__(256) void k_agg2(const float* __restrict__ h,
                                              const int* __restrict__ ebuf,
                                              const int* __restrict__ start,
                                              const int* __restrict__ cnt,
                                              const float* __restrict__ dinv,
                                              const float* __restrict__ b2,
                                              float* __restrict__ out, int Nn) {
    int node = __builtin_amdgcn_readfirstlane(blockIdx.x * 4 + (threadIdx.x >> 6));
    int lane = threadIdx.x & 63;
    if (node >= Nn) return;
    int rs = start[node];
    int n  = cnt[node];
    float di = dinv[node];
    float acc = 0.f;
    bool active = (lane < FOUT);
    int lidx = active ? lane : 0;         // keep loads in-bounds for inactive lanes
    int k = 0;
    for (; k + 4 <= n; k += 4) {
        int s0 = ebuf[rs + k + 0];
        int s1 = ebuf[rs + k + 1];
        int s2 = ebuf[rs + k + 2];
        int s3 = ebuf[rs + k + 3];
        float w0 = dinv[s0], w1 = dinv[s1], w2 = dinv[s2], w3 = dinv[s3];
        float v0 = h[(size_t)s0 * FOUT + lidx];
        float v1 = h[(size_t)s1 * FOUT + lidx];
        float v2 = h[(size_t)s2 * FOUT + lidx];
        float v3 = h[(size_t)s3 * FOUT + lidx];
        acc += w0 * v0 + w1 * v1 + w2 * v2 + w3 * v3;
    }
    for (; k < n; ++k) {
        int s   = ebuf[rs + k];
        acc += dinv[s] * h[(size_t)s * FOUT + lidx];
    }
    float v = active ? di * acc + b2[lane] : -INFINITY;
    float m = v;
    #pragma unroll
    for (int off = 32; off >= 1; off >>= 1) m = fmaxf(m, __shfl_xor(m, off));
    float e = active ? expf(v - m) : 0.f;
    float ssum = e;
    #pragma unroll
    for (int off = 32; off >= 1; off >>= 1) ssum += __shfl_xor(ssum, off);
    if (active) out[(size_t)node * FOUT + lane] = v - m - logf(ssum);
}

extern "C" void kernel_launch(void* const* d_in, const int* in_sizes, int n_in,
                              void* d_out, int out_size, void* d_ws, size_t ws_size,
                              hipStream_t stream) {
    const float* x  = (const float*)d_in[0];
    const int*   ei = (const int*)d_in[1];
    const float* W1 = (const float*)d_in[2];
    const float* b1 = (const float*)d_in[3];
    const float* W2 = (const float*)d_in[4];
    const float* b2 = (const float*)d_in[5];

    const int N = in_sizes[0] / FIN;     // 100000
    const int E = in_sizes[1] / 2;       // 1600000
    float* out = (float*)d_out;

    // workspace layout (~85 MB)
    ushort* h1b   = (ushort*)d_ws;                     // N*128 bf16
    float*  agg1  = (float*)(h1b + (size_t)N * FMID);  // N*128 f32
    float*  dinv  = agg1 + (size_t)N * FMID;           // N f32
    int*    counts= (int*)(dinv + N);                  // N int
    int*    start = counts + N;                        // N int
    int*    gcnt  = start + N;                         // 1 int (+pad)
    int*    ebuf  = gcnt + 64;                         // E+N int
    short*  w1t   = (short*)(ebuf + (size_t)(E + N));  // 128*256 bf16
    float*  h2    = (float*)h1b;                       // alias: h1b dead after k_agg1

    const int* srcp = ei;
    const int* dstp = ei + E;
    const int  EN   = E + N;

    // ---- W1 prep (independent) ----
    k_prepw1<<<(FIN * FMID + 255) / 256, 256, 0, stream>>>(W1, w1t);

    // ---- CSR build ----
    hipMemsetAsync(gcnt, 0, sizeof(int), stream);
    k_initcounts<<<(N + 255) / 256, 256, 0, stream>>>(counts, N);
    k_count     <<<(E + 255) / 256, 256, 0, stream>>>(dstp, counts, E);
    k_alloc     <<<(N + 255) / 256, 256, 0, stream>>>(counts, start, dinv, gcnt, N);
    hipMemsetAsync(counts, 0, (size_t)N * sizeof(int), stream);   // reuse as cursor
    k_fill      <<<(EN + 255) / 256, 256, 0, stream>>>(srcp, dstp, start, counts, ebuf, E, N);

    // ---- layer 1 ----
    k_gemm1b<<<(N + 127) / 128, 256, 0, stream>>>(x, w1t, h1b, N);
    k_agg1  <<<(N + 3) / 4, 256, 0, stream>>>(h1b, ebuf, start, counts, dinv, b1, agg1, N);

    // ---- layer 2 ----
    k_gemm2<<<(N + 63) / 64, 256, 0, stream>>>(agg1, W2, h2, N);
    k_agg2 <<<(N + 3) / 4, 256, 0, stream>>>(h2, ebuf, start, counts, dinv, b2, out, N);
}

// Round 12
// 475.873 us; speedup vs baseline: 5.5723x; 1.0968x over previous
//
#include <hip/hip_runtime.h>
#include <hip/hip_bf16.h>
#include <math.h>

#define FIN 256
#define FMID 128
#define FOUT 40

typedef __attribute__((ext_vector_type(8))) short bf16x8;
typedef __attribute__((ext_vector_type(4))) float f32x4;

__device__ __forceinline__ short f2b(float f) {
    __hip_bfloat16 h = __float2bfloat16(f);
    return *reinterpret_cast<short*>(&h);
}

__device__ __forceinline__ float blo(uint b) { union { uint u; float f; } v; v.u = b << 16; return v.f; }
__device__ __forceinline__ float bhi(uint b) { union { uint u; float f; } v; v.u = b & 0xFFFF0000u; return v.f; }

// ================= CSR build =================
// counts zeroed via memset. pos[e] = slot of edge e within its dst bucket
// (the atomicAdd return value) -> k_fill2 needs NO atomics.
__global__ __launch_bounds__(256) void k_count_pos(const int* __restrict__ dst,
                                                   int* __restrict__ counts,
                                                   int* __restrict__ pos, int E) {
    int e = blockIdx.x * 256 + threadIdx.x;
    if (e < E) pos[e] = atomicAdd(&counts[dst[e]], 1);
}

// scan over (edge_count+1); writes start, dinv, self-loop into ebuf slot 0,
// and overwrites counts[i] with the FULL count (incl self-loop) for the aggs.
__global__ __launch_bounds__(256) void k_alloc(int* __restrict__ counts,
                                               int* __restrict__ start,
                                               float* __restrict__ dinv,
                                               int* __restrict__ gcnt,
                                               int* __restrict__ ebuf, int n) {
    __shared__ int s[256];
    __shared__ int base_s;
    int t = threadIdx.x;
    int i = blockIdx.x * 256 + t;
    int c = (i < n) ? counts[i] + 1 : 0;   // +1 self-loop
    s[t] = c;
    __syncthreads();
    #pragma unroll
    for (int off = 1; off < 256; off <<= 1) {
        int v = (t >= off) ? s[t - off] : 0;
        __syncthreads();
        s[t] += v;
        __syncthreads();
    }
    if (t == 255) base_s = atomicAdd(gcnt, s[255]);
    __syncthreads();
    if (i < n) {
        int st = base_s + s[t] - c;
        start[i]  = st;
        dinv[i]   = rsqrtf((float)c);
        counts[i] = c;          // full count for agg kernels
        ebuf[st]  = i;          // self-loop at slot 0
    }
}

__global__ __launch_bounds__(256) void k_fill2(const int* __restrict__ src,
                                               const int* __restrict__ dst,
                                               const int* __restrict__ start,
                                               const int* __restrict__ pos,
                                               int* __restrict__ ebuf, int E) {
    int e = blockIdx.x * 256 + threadIdx.x;
    if (e >= E) return;
    int d = dst[e];
    ebuf[start[d] + 1 + pos[e]] = src[e];
}

// ============ W1 -> bf16, transposed: w1t[n][k], n<128, k<256 ============
__global__ __launch_bounds__(256) void k_prepw1(const float* __restrict__ W1,
                                                short* __restrict__ w1t) {
    int t = blockIdx.x * 256 + threadIdx.x;   // 32768 total
    if (t >= FIN * FMID) return;
    int k = t >> 7;           // 0..255
    int n = t & 127;          // 0..127
    w1t[n * FIN + k] = f2b(W1[t]);
}

// ========== GEMM1 (MFMA bf16): [M,256]f32 x W1 -> [M,128]bf16 ==========
__global__ __launch_bounds__(256) void k_gemm1b(const float* __restrict__ A,
                                                const short* __restrict__ w1t,
                                                ushort* __restrict__ Cb, int M) {
    __shared__ short Bs[FMID * FIN];          // 64 KB

    const int t = threadIdx.x;
    {
        int c  = t & 31;
        int r0 = t >> 5;
        #pragma unroll
        for (int p = 0; p < 16; ++p) {
            int n = r0 + p * 8;
            int dst = n * FIN + ((c * 8) ^ ((n & 7) << 3));
            *(bf16x8*)(&Bs[dst]) = *(const bf16x8*)(&w1t[n * FIN + c * 8]);
        }
    }
    __syncthreads();

    const int wid  = t >> 6;
    const int lane = t & 63;
    const int l15  = lane & 15;
    const int kg   = lane >> 4;
    const int mbase = blockIdx.x * 128 + wid * 32;

    f32x4 acc[2][8] = {};

    for (int ks = 0; ks < 8; ++ks) {
        const int k0 = ks * 32;
        bf16x8 bf[8];
        #pragma unroll
        for (int ct = 0; ct < 8; ++ct) {
            int n = ct * 16 + l15;
            bf[ct] = *(const bf16x8*)(&Bs[n * FIN + ((k0 + kg * 8) ^ ((n & 7) << 3))]);
        }
        #pragma unroll
        for (int rt = 0; rt < 2; ++rt) {
            int row = mbase + rt * 16 + l15;
            bf16x8 af = {0, 0, 0, 0, 0, 0, 0, 0};
            if (row < M) {
                const float* ap = &A[(size_t)row * FIN + k0 + kg * 8];
                float4 a0 = *(const float4*)(ap);
                float4 a1 = *(const float4*)(ap + 4);
                af[0] = f2b(a0.x); af[1] = f2b(a0.y);
                af[2] = f2b(a0.z); af[3] = f2b(a0.w);
                af[4] = f2b(a1.x); af[5] = f2b(a1.y);
                af[6] = f2b(a1.z); af[7] = f2b(a1.w);
            }
            #pragma unroll
            for (int ct = 0; ct < 8; ++ct)
                acc[rt][ct] = __builtin_amdgcn_mfma_f32_16x16x32_bf16(
                    af, bf[ct], acc[rt][ct], 0, 0, 0);
        }
    }

    #pragma unroll
    for (int rt = 0; rt < 2; ++rt) {
        #pragma unroll
        for (int r = 0; r < 4; ++r) {
            int row = mbase + rt * 16 + kg * 4 + r;
            if (row < M) {
                #pragma unroll
                for (int ct = 0; ct < 8; ++ct)
                    Cb[(size_t)row * FMID + ct * 16 + l15] =
                        (ushort)f2b(acc[rt][ct][r]);
            }
        }
    }
}

// ====== agg1 (CSR gather, bf16 h, F=128) + bias + relu, one wave per node ======
__global__ __launch_bounds__(256) void k_agg1(const ushort* __restrict__ hb,
                                              const int* __restrict__ ebuf,
                                              const int* __restrict__ start,
                                              const int* __restrict__ cnt,
                                              const float* __restrict__ dinv,
                                              const float* __restrict__ b1,
                                              float* __restrict__ out, int Nn) {
    int node = __builtin_amdgcn_readfirstlane(blockIdx.x * 4 + (threadIdx.x >> 6));
    int lane = threadIdx.x & 63;
    if (node >= Nn) return;
    int rs = start[node];
    int n  = cnt[node];
    float di = dinv[node];
    float2 acc = make_float2(0.f, 0.f);
    const int off2 = lane * 2;
    int k = 0;
    for (; k + 4 <= n; k += 4) {
        int s0 = ebuf[rs + k + 0];
        int s1 = ebuf[rs + k + 1];
        int s2 = ebuf[rs + k + 2];
        int s3 = ebuf[rs + k + 3];
        float w0 = dinv[s0], w1 = dinv[s1], w2 = dinv[s2], w3 = dinv[s3];
        uint v0 = *(const uint*)(&hb[(size_t)s0 * FMID + off2]);
        uint v1 = *(const uint*)(&hb[(size_t)s1 * FMID + off2]);
        uint v2 = *(const uint*)(&hb[(size_t)s2 * FMID + off2]);
        uint v3 = *(const uint*)(&hb[(size_t)s3 * FMID + off2]);
        acc.x += w0 * blo(v0) + w1 * blo(v1) + w2 * blo(v2) + w3 * blo(v3);
        acc.y += w0 * bhi(v0) + w1 * bhi(v1) + w2 * bhi(v2) + w3 * bhi(v3);
    }
    for (; k < n; ++k) {
        int s   = ebuf[rs + k];
        float w = dinv[s];
        uint v  = *(const uint*)(&hb[(size_t)s * FMID + off2]);
        acc.x += w * blo(v);
        acc.y += w * bhi(v);
    }
    float2 bv = *(const float2*)(&b1[off2]);
    acc.x = fmaxf(di * acc.x + bv.x, 0.f);
    acc.y = fmaxf(di * acc.y + bv.y, 0.f);
    *(float2*)(&out[(size_t)node * FMID + off2]) = acc;
}

// ========== GEMM2: [M,128] x [128,40] -> [M,40] (f32) ==========
// float4-vectorized LDS reads (224 LDS instrs/thread vs 896 scalar before):
// W2 transposed in LDS (w2t[j][k], stride 132 -> cg groups hit disjoint
// bank-quads); A tile row-major stride 132 (2-way aliasing = free, m136).
#define G2_PAD 132
__global__ __launch_bounds__(256) void k_gemm2(const float* __restrict__ A,
                                               const float* __restrict__ W2,
                                               float* __restrict__ C, int M) {
    __shared__ float w2t[FOUT * G2_PAD];      // 21 KB, [j][k]
    __shared__ float As[64 * G2_PAD];         // 33 KB

    const int t = threadIdx.x;
    const int block_row = blockIdx.x * 64;

    for (int idx = t; idx < FMID * FOUT; idx += 256) {
        int k = idx / FOUT;
        int j = idx - k * FOUT;
        w2t[j * G2_PAD + k] = W2[idx];
    }

    {
        int r  = t >> 5;
        int c4 = (t & 31) * 4;
        #pragma unroll
        for (int p = 0; p < 8; ++p) {
            int row = block_row + r + p * 8;
            float4 v = (row < M) ? *(const float4*)(&A[(size_t)row * FMID + c4])
                                 : make_float4(0.f, 0.f, 0.f, 0.f);
            *(float4*)(&As[(r + p * 8) * G2_PAD + c4]) = v;
        }
    }
    __syncthreads();

    const int cg    = t & 7;
    const int rg    = t >> 3;
    const int cbase = cg * 5;
    const float* a0p = &As[(rg * 2 + 0) * G2_PAD];
    const float* a1p = &As[(rg * 2 + 1) * G2_PAD];

    float acc0[5] = {}, acc1[5] = {};
    #pragma unroll 4
    for (int k = 0; k < FMID; k += 4) {
        float4 a0 = *(const float4*)(a0p + k);
        float4 a1 = *(const float4*)(a1p + k);
        #pragma unroll
        for (int j = 0; j < 5; ++j) {
            float4 w = *(const float4*)(&w2t[(cbase + j) * G2_PAD + k]);
            acc0[j] += a0.x * w.x + a0.y * w.y + a0.z * w.z + a0.w * w.w;
            acc1[j] += a1.x * w.x + a1.y * w.y + a1.z * w.z + a1.w * w.w;
        }
    }

    int row0 = block_row + rg * 2;
    if (row0 < M) {
        #pragma unroll
        for (int j = 0; j < 5; ++j) C[(size_t)row0 * FOUT + cbase + j] = acc0[j];
    }
    if (row0 + 1 < M) {
        #pragma unroll
        for (int j = 0; j < 5; ++j) C[(size_t)(row0 + 1) * FOUT + cbase + j] = acc1[j];
    }
}

// ====== agg2 (CSR gather, F=40) + bias + log_softmax -> d_out, 4x unrolled ======
__global__ __launch_bounds__(256) void k_agg2(const float* __restrict__ h,
                                              const int* __restrict__ ebuf,
                                              const int* __restrict__ start,
                                              const int* __restrict__ cnt,
                                              const float* __restrict__ dinv,
                                              const float* __restrict__ b2,
                                              float* __restrict__ out, int Nn) {
    int node = __builtin_amdgcn_readfirstlane(blockIdx.x * 4 + (threadIdx.x >> 6));
    int lane = threadIdx.x & 63;
    if (node >= Nn) return;
    int rs = start[node];
    int n  = cnt[node];
    float di = dinv[node];
    float acc = 0.f;
    bool active = (lane < FOUT);
    int lidx = active ? lane : 0;
    int k = 0;
    for (; k + 4 <= n; k += 4) {
        int s0 = ebuf[rs + k + 0];
        int s1 = ebuf[rs + k + 1];
        int s2 = ebuf[rs + k + 2];
        int s3 = ebuf[rs + k + 3];
        float w0 = dinv[s0], w1 = dinv[s1], w2 = dinv[s2], w3 = dinv[s3];
        float v0 = h[(size_t)s0 * FOUT + lidx];
        float v1 = h[(size_t)s1 * FOUT + lidx];
        float v2 = h[(size_t)s2 * FOUT + lidx];
        float v3 = h[(size_t)s3 * FOUT + lidx];
        acc += w0 * v0 + w1 * v1 + w2 * v2 + w3 * v3;
    }
    for (; k < n; ++k) {
        int s   = ebuf[rs + k];
        acc += dinv[s] * h[(size_t)s * FOUT + lidx];
    }
    float v = active ? di * acc + b2[lane] : -INFINITY;
    float m = v;
    #pragma unroll
    for (int off = 32; off >= 1; off >>= 1) m = fmaxf(m, __shfl_xor(m, off));
    float e = active ? expf(v - m) : 0.f;
    float ssum = e;
    #pragma unroll
    for (int off = 32; off >= 1; off >>= 1) ssum += __shfl_xor(ssum, off);
    if (active) out[(size_t)node * FOUT + lane] = v - m - logf(ssum);
}

extern "C" void kernel_launch(void* const* d_in, const int* in_sizes, int n_in,
                              void* d_out, int out_size, void* d_ws, size_t ws_size,
                              hipStream_t stream) {
    const float* x  = (const float*)d_in[0];
    const int*   ei = (const int*)d_in[1];
    const float* W1 = (const float*)d_in[2];
    const float* b1 = (const float*)d_in[3];
    const float* W2 = (const float*)d_in[4];
    const float* b2 = (const float*)d_in[5];

    const int N = in_sizes[0] / FIN;     // 100000
    const int E = in_sizes[1] / 2;       // 1600000
    float* out = (float*)d_out;

    // workspace layout (~98 MB)
    ushort* h1b   = (ushort*)d_ws;                     // N*128 bf16
    float*  agg1  = (float*)(h1b + (size_t)N * FMID);  // N*128 f32
    float*  dinv  = agg1 + (size_t)N * FMID;           // N f32
    int*    counts= (int*)(dinv + N);                  // N int
    int*    start = counts + N;                        // N int
    int*    gcnt  = start + N;                         // 1 int (+pad)
    int*    ebuf  = gcnt + 64;                         // E+N int
    short*  w1t   = (short*)(ebuf + (size_t)(E + N));  // 128*256 bf16
    int*    pos   = (int*)(w1t + FIN * FMID);          // E int
    float*  h2    = (float*)h1b;                       // alias: h1b dead after k_agg1

    const int* srcp = ei;
    const int* dstp = ei + E;

    // ---- W1 prep (independent) ----
    k_prepw1<<<(FIN * FMID + 255) / 256, 256, 0, stream>>>(W1, w1t);

    // ---- CSR build (one atomic pass) ----
    hipMemsetAsync(gcnt, 0, sizeof(int), stream);
    hipMemsetAsync(counts, 0, (size_t)N * sizeof(int), stream);
    k_count_pos<<<(E + 255) / 256, 256, 0, stream>>>(dstp, counts, pos, E);
    k_alloc    <<<(N + 255) / 256, 256, 0, stream>>>(counts, start, dinv, gcnt, ebuf, N);
    k_fill2    <<<(E + 255) / 256, 256, 0, stream>>>(srcp, dstp, start, pos, ebuf, E);

    // ---- layer 1 ----
    k_gemm1b<<<(N + 127) / 128, 256, 0, stream>>>(x, w1t, h1b, N);
    k_agg1  <<<(N + 3) / 4, 256, 0, stream>>>(h1b, ebuf, start, counts, dinv, b1, agg1, N);

    // ---- layer 2 ----
    k_gemm2<<<(N + 63) / 64, 256, 0, stream>>>(agg1, W2, h2, N);
    k_agg2 <<<(N + 3) / 4, 256, 0, stream>>>(h2, ebuf, start, counts, dinv, b2, out, N);
}

// Round 14
// 468.101 us; speedup vs baseline: 5.6648x; 1.0166x over previous
//
#include <hip/hip_runtime.h>
#include <hip/hip_bf16.h>
#include <math.h>

#define FIN 256
#define FMID 128
#define FOUT 40

typedef __attribute__((ext_vector_type(8))) short bf16x8;
typedef __attribute__((ext_vector_type(4))) float f32x4;

__device__ __forceinline__ short f2b(float f) {
    __hip_bfloat16 h = __float2bfloat16(f);
    return *reinterpret_cast<short*>(&h);
}

__device__ __forceinline__ float blo(uint b) { union { uint u; float f; } v; v.u = b << 16; return v.f; }
__device__ __forceinline__ float bhi(uint b) { union { uint u; float f; } v; v.u = b & 0xFFFF0000u; return v.f; }

// ================= CSR build =================
// 4x grid-stride batch: 4 independent atomic chains in flight per thread
// (count_pos was 1 atomic/thread, latency-bound: 75us, VALU 0.4%, HBM 10%).
__global__ __launch_bounds__(256) void k_count_pos(const int* __restrict__ dst,
                                                   int* __restrict__ counts,
                                                   int* __restrict__ pos, int E) {
    int tid    = blockIdx.x * 256 + threadIdx.x;
    int stride = gridDim.x * 256;
    int e0 = tid, e1 = tid + stride, e2 = tid + 2 * stride, e3 = tid + 3 * stride;
    int d0 = (e0 < E) ? dst[e0] : 0;
    int d1 = (e1 < E) ? dst[e1] : 0;
    int d2 = (e2 < E) ? dst[e2] : 0;
    int d3 = (e3 < E) ? dst[e3] : 0;
    int p0, p1, p2, p3;
    if (e0 < E) p0 = atomicAdd(&counts[d0], 1);
    if (e1 < E) p1 = atomicAdd(&counts[d1], 1);
    if (e2 < E) p2 = atomicAdd(&counts[d2], 1);
    if (e3 < E) p3 = atomicAdd(&counts[d3], 1);
    if (e0 < E) pos[e0] = p0;
    if (e1 < E) pos[e1] = p1;
    if (e2 < E) pos[e2] = p2;
    if (e3 < E) pos[e3] = p3;
}

// scan over (edge_count+1); writes start, dinv, self-loop into ebuf slot 0,
// and overwrites counts[i] with the FULL count (incl self-loop) for the aggs.
__global__ __launch_bounds__(256) void k_alloc(int* __restrict__ counts,
                                               int* __restrict__ start,
                                               float* __restrict__ dinv,
                                               int* __restrict__ gcnt,
                                               int* __restrict__ ebuf, int n) {
    __shared__ int s[256];
    __shared__ int base_s;
    int t = threadIdx.x;
    int i = blockIdx.x * 256 + t;
    int c = (i < n) ? counts[i] + 1 : 0;   // +1 self-loop
    s[t] = c;
    __syncthreads();
    #pragma unroll
    for (int off = 1; off < 256; off <<= 1) {
        int v = (t >= off) ? s[t - off] : 0;
        __syncthreads();
        s[t] += v;
        __syncthreads();
    }
    if (t == 255) base_s = atomicAdd(gcnt, s[255]);
    __syncthreads();
    if (i < n) {
        int st = base_s + s[t] - c;
        start[i]  = st;
        dinv[i]   = rsqrtf((float)c);
        counts[i] = c;          // full count for agg kernels
        ebuf[st]  = i;          // self-loop at slot 0
    }
}

// 4x grid-stride batch, no atomics.
__global__ __launch_bounds__(256) void k_fill2(const int* __restrict__ src,
                                               const int* __restrict__ dst,
                                               const int* __restrict__ start,
                                               const int* __restrict__ pos,
                                               int* __restrict__ ebuf, int E) {
    int tid    = blockIdx.x * 256 + threadIdx.x;
    int stride = gridDim.x * 256;
    int e0 = tid, e1 = tid + stride, e2 = tid + 2 * stride, e3 = tid + 3 * stride;
    bool v0 = e0 < E, v1 = e1 < E, v2 = e2 < E, v3 = e3 < E;
    int d0 = v0 ? dst[e0] : 0;
    int d1 = v1 ? dst[e1] : 0;
    int d2 = v2 ? dst[e2] : 0;
    int d3 = v3 ? dst[e3] : 0;
    int p0 = v0 ? pos[e0] : 0;
    int p1 = v1 ? pos[e1] : 0;
    int p2 = v2 ? pos[e2] : 0;
    int p3 = v3 ? pos[e3] : 0;
    int s0 = v0 ? src[e0] : 0;
    int s1 = v1 ? src[e1] : 0;
    int s2 = v2 ? src[e2] : 0;
    int s3 = v3 ? src[e3] : 0;
    int st0 = v0 ? start[d0] : 0;
    int st1 = v1 ? start[d1] : 0;
    int st2 = v2 ? start[d2] : 0;
    int st3 = v3 ? start[d3] : 0;
    if (v0) ebuf[st0 + 1 + p0] = s0;
    if (v1) ebuf[st1 + 1 + p1] = s1;
    if (v2) ebuf[st2 + 1 + p2] = s2;
    if (v3) ebuf[st3 + 1 + p3] = s3;
}

// ============ W1 -> bf16, transposed: w1t[n][k], n<128, k<256 ============
__global__ __launch_bounds__(256) void k_prepw1(const float* __restrict__ W1,
                                                short* __restrict__ w1t) {
    int t = blockIdx.x * 256 + threadIdx.x;   // 32768 total
    if (t >= FIN * FMID) return;
    int k = t >> 7;           // 0..255
    int n = t & 127;          // 0..127
    w1t[n * FIN + k] = f2b(W1[t]);
}

// ========== GEMM1 (MFMA bf16): [M,256]f32 x W1 -> [M,128]bf16, PRE-SCALED by dinv[row] ==========
__global__ __launch_bounds__(256) void k_gemm1b(const float* __restrict__ A,
                                                const short* __restrict__ w1t,
                                                const float* __restrict__ dinv,
                                                ushort* __restrict__ Cb, int M) {
    __shared__ short Bs[FMID * FIN];          // 64 KB

    const int t = threadIdx.x;
    {
        int c  = t & 31;
        int r0 = t >> 5;
        #pragma unroll
        for (int p = 0; p < 16; ++p) {
            int n = r0 + p * 8;
            int dst = n * FIN + ((c * 8) ^ ((n & 7) << 3));
            *(bf16x8*)(&Bs[dst]) = *(const bf16x8*)(&w1t[n * FIN + c * 8]);
        }
    }
    __syncthreads();

    const int wid  = t >> 6;
    const int lane = t & 63;
    const int l15  = lane & 15;
    const int kg   = lane >> 4;
    const int mbase = blockIdx.x * 128 + wid * 32;

    f32x4 acc[2][8] = {};

    for (int ks = 0; ks < 8; ++ks) {
        const int k0 = ks * 32;
        bf16x8 bf[8];
        #pragma unroll
        for (int ct = 0; ct < 8; ++ct) {
            int n = ct * 16 + l15;
            bf[ct] = *(const bf16x8*)(&Bs[n * FIN + ((k0 + kg * 8) ^ ((n & 7) << 3))]);
        }
        #pragma unroll
        for (int rt = 0; rt < 2; ++rt) {
            int row = mbase + rt * 16 + l15;
            bf16x8 af = {0, 0, 0, 0, 0, 0, 0, 0};
            if (row < M) {
                const float* ap = &A[(size_t)row * FIN + k0 + kg * 8];
                float4 a0 = *(const float4*)(ap);
                float4 a1 = *(const float4*)(ap + 4);
                af[0] = f2b(a0.x); af[1] = f2b(a0.y);
                af[2] = f2b(a0.z); af[3] = f2b(a0.w);
                af[4] = f2b(a1.x); af[5] = f2b(a1.y);
                af[6] = f2b(a1.z); af[7] = f2b(a1.w);
            }
            #pragma unroll
            for (int ct = 0; ct < 8; ++ct)
                acc[rt][ct] = __builtin_amdgcn_mfma_f32_16x16x32_bf16(
                    af, bf[ct], acc[rt][ct], 0, 0, 0);
        }
    }

    #pragma unroll
    for (int rt = 0; rt < 2; ++rt) {
        #pragma unroll
        for (int r = 0; r < 4; ++r) {
            int row = mbase + rt * 16 + kg * 4 + r;
            if (row < M) {
                float sc = dinv[row];
                #pragma unroll
                for (int ct = 0; ct < 8; ++ct)
                    Cb[(size_t)row * FMID + ct * 16 + l15] =
                        (ushort)f2b(acc[rt][ct][r] * sc);
            }
        }
    }
}

// ====== agg1: h rows pre-scaled by dinv[s] -> only 2 loads per edge ======
__global__ __launch_bounds__(256) void k_agg1(const ushort* __restrict__ hb,
                                              const int* __restrict__ ebuf,
                                              const int* __restrict__ start,
                                              const int* __restrict__ cnt,
                                              const float* __restrict__ dinv,
                                              const float* __restrict__ b1,
                                              float* __restrict__ out, int Nn) {
    int node = __builtin_amdgcn_readfirstlane(blockIdx.x * 4 + (threadIdx.x >> 6));
    int lane = threadIdx.x & 63;
    if (node >= Nn) return;
    int rs = start[node];
    int n  = cnt[node];
    float di = dinv[node];
    float2 acc = make_float2(0.f, 0.f);
    const int off2 = lane * 2;
    int k = 0;
    for (; k + 4 <= n; k += 4) {
        int s0 = ebuf[rs + k + 0];
        int s1 = ebuf[rs + k + 1];
        int s2 = ebuf[rs + k + 2];
        int s3 = ebuf[rs + k + 3];
        uint v0 = *(const uint*)(&hb[(size_t)s0 * FMID + off2]);
        uint v1 = *(const uint*)(&hb[(size_t)s1 * FMID + off2]);
        uint v2 = *(const uint*)(&hb[(size_t)s2 * FMID + off2]);
        uint v3 = *(const uint*)(&hb[(size_t)s3 * FMID + off2]);
        acc.x += blo(v0) + blo(v1) + blo(v2) + blo(v3);
        acc.y += bhi(v0) + bhi(v1) + bhi(v2) + bhi(v3);
    }
    for (; k < n; ++k) {
        int s   = ebuf[rs + k];
        uint v  = *(const uint*)(&hb[(size_t)s * FMID + off2]);
        acc.x += blo(v);
        acc.y += bhi(v);
    }
    float2 bv = *(const float2*)(&b1[off2]);
    acc.x = fmaxf(di * acc.x + bv.x, 0.f);
    acc.y = fmaxf(di * acc.y + bv.y, 0.f);
    *(float2*)(&out[(size_t)node * FMID + off2]) = acc;
}

// ========== GEMM2: [M,128] x [128,40] -> [M,40] (f32), output PRE-SCALED by dinv[row] ==========
#define G2_PAD 132
__global__ __launch_bounds__(256) void k_gemm2(const float* __restrict__ A,
                                               const float* __restrict__ W2,
                                               const float* __restrict__ dinv,
                                               float* __restrict__ C, int M) {
    __shared__ float w2t[FOUT * G2_PAD];      // 21 KB, [j][k]
    __shared__ float As[64 * G2_PAD];         // 33 KB

    const int t = threadIdx.x;
    const int block_row = blockIdx.x * 64;

    for (int idx = t; idx < FMID * FOUT; idx += 256) {
        int k = idx / FOUT;
        int j = idx - k * FOUT;
        w2t[j * G2_PAD + k] = W2[idx];
    }

    {
        int r  = t >> 5;
        int c4 = (t & 31) * 4;
        #pragma unroll
        for (int p = 0; p < 8; ++p) {
            int row = block_row + r + p * 8;
            float4 v = (row < M) ? *(const float4*)(&A[(size_t)row * FMID + c4])
                                 : make_float4(0.f, 0.f, 0.f, 0.f);
            *(float4*)(&As[(r + p * 8) * G2_PAD + c4]) = v;
        }
    }
    __syncthreads();

    const int cg    = t & 7;
    const int rg    = t >> 3;
    const int cbase = cg * 5;
    const float* a0p = &As[(rg * 2 + 0) * G2_PAD];
    const float* a1p = &As[(rg * 2 + 1) * G2_PAD];

    float acc0[5] = {}, acc1[5] = {};
    #pragma unroll 4
    for (int k = 0; k < FMID; k += 4) {
        float4 a0 = *(const float4*)(a0p + k);
        float4 a1 = *(const float4*)(a1p + k);
        #pragma unroll
        for (int j = 0; j < 5; ++j) {
            float4 w = *(const float4*)(&w2t[(cbase + j) * G2_PAD + k]);
            acc0[j] += a0.x * w.x + a0.y * w.y + a0.z * w.z + a0.w * w.w;
            acc1[j] += a1.x * w.x + a1.y * w.y + a1.z * w.z + a1.w * w.w;
        }
    }

    int row0 = block_row + rg * 2;
    if (row0 < M) {
        float sc = dinv[row0];
        #pragma unroll
        for (int j = 0; j < 5; ++j) C[(size_t)row0 * FOUT + cbase + j] = acc0[j] * sc;
    }
    if (row0 + 1 < M) {
        float sc = dinv[row0 + 1];
        #pragma unroll
        for (int j = 0; j < 5; ++j) C[(size_t)(row0 + 1) * FOUT + cbase + j] = acc1[j] * sc;
    }
}

// ====== agg2: h2 pre-scaled -> 2 loads per edge; + bias + log_softmax ======
__global__ __launch_bounds__(256) void k_agg2(const float* __restrict__ h,
                                              const int* __restrict__ ebuf,
                                              const int* __restrict__ start,
                                              const int* __restrict__ cnt,
                                              const float* __restrict__ dinv,
                                              const float* __restrict__ b2,
                                              float* __restrict__ out, int Nn) {
    int node = __builtin_amdgcn_readfirstlane(blockIdx.x * 4 + (threadIdx.x >> 6));
    int lane = threadIdx.x & 63;
    if (node >= Nn) return;
    int rs = start[node];
    int n  = cnt[node];
    float di = dinv[node];
    float acc = 0.f;
    bool active = (lane < FOUT);
    int lidx = active ? lane : 0;
    int k = 0;
    for (; k + 4 <= n; k += 4) {
        int s0 = ebuf[rs + k + 0];
        int s1 = ebuf[rs + k + 1];
        int s2 = ebuf[rs + k + 2];
        int s3 = ebuf[rs + k + 3];
        float v0 = h[(size_t)s0 * FOUT + lidx];
        float v1 = h[(size_t)s1 * FOUT + lidx];
        float v2 = h[(size_t)s2 * FOUT + lidx];
        float v3 = h[(size_t)s3 * FOUT + lidx];
        acc += v0 + v1 + v2 + v3;
    }
    for (; k < n; ++k) {
        int s = ebuf[rs + k];
        acc += h[(size_t)s * FOUT + lidx];
    }
    float v = active ? di * acc + b2[lane] : -INFINITY;
    float m = v;
    #pragma unroll
    for (int off = 32; off >= 1; off >>= 1) m = fmaxf(m, __shfl_xor(m, off));
    float e = active ? expf(v - m) : 0.f;
    float ssum = e;
    #pragma unroll
    for (int off = 32; off >= 1; off >>= 1) ssum += __shfl_xor(ssum, off);
    if (active) out[(size_t)node * FOUT + lane] = v - m - logf(ssum);
}

extern "C" void kernel_launch(void* const* d_in, const int* in_sizes, int n_in,
                              void* d_out, int out_size, void* d_ws, size_t ws_size,
                              hipStream_t stream) {
    const float* x  = (const float*)d_in[0];
    const int*   ei = (const int*)d_in[1];
    const float* W1 = (const float*)d_in[2];
    const float* b1 = (const float*)d_in[3];
    const float* W2 = (const float*)d_in[4];
    const float* b2 = (const float*)d_in[5];

    const int N = in_sizes[0] / FIN;     // 100000
    const int E = in_sizes[1] / 2;       // 1600000
    float* out = (float*)d_out;

    // workspace layout (~98 MB)
    ushort* h1b   = (ushort*)d_ws;                     // N*128 bf16
    float*  agg1  = (float*)(h1b + (size_t)N * FMID);  // N*128 f32
    float*  dinv  = agg1 + (size_t)N * FMID;           // N f32
    int*    counts= (int*)(dinv + N);                  // N int
    int*    start = counts + N;                        // N int
    int*    gcnt  = start + N;                         // 1 int (+pad)
    int*    ebuf  = gcnt + 64;                         // E+N int
    short*  w1t   = (short*)(ebuf + (size_t)(E + N));  // 128*256 bf16
    int*    pos   = (int*)(w1t + FIN * FMID);          // E int
    float*  h2    = (float*)h1b;                       // alias: h1b dead after k_agg1

    const int* srcp = ei;
    const int* dstp = ei + E;

    // ---- W1 prep (independent) ----
    k_prepw1<<<(FIN * FMID + 255) / 256, 256, 0, stream>>>(W1, w1t);

    // ---- CSR build (one atomic pass, 4x batched) ----
    hipMemsetAsync(gcnt, 0, sizeof(int), stream);
    hipMemsetAsync(counts, 0, (size_t)N * sizeof(int), stream);
    k_count_pos<<<(E + 1023) / 1024, 256, 0, stream>>>(dstp, counts, pos, E);
    k_alloc    <<<(N + 255) / 256, 256, 0, stream>>>(counts, start, dinv, gcnt, ebuf, N);
    k_fill2    <<<(E + 1023) / 1024, 256, 0, stream>>>(srcp, dstp, start, pos, ebuf, E);

    // ---- layer 1 ----
    k_gemm1b<<<(N + 127) / 128, 256, 0, stream>>>(x, w1t, dinv, h1b, N);
    k_agg1  <<<(N + 3) / 4, 256, 0, stream>>>(h1b, ebuf, start, counts, dinv, b1, agg1, N);

    // ---- layer 2 ----
    k_gemm2<<<(N + 63) / 64, 256, 0, stream>>>(agg1, W2, dinv, h2, N);
    k_agg2 <<<(N + 3) / 4, 256, 0, stream>>>(h2, ebuf, start, counts, dinv, b2, out, N);
}